// Round 18
// baseline (297.209 us; speedup 1.0000x reference)
//
#include <hip/hip_runtime.h>
#include <hip/hip_bf16.h>
#include <math.h>

#define BB   2
#define NN   32768
#define DIN  768
#define DD   512
#define PP   16
#define MTOT (BB*NN)          // rows per side
#define MALL (2*MTOT)         // both sides
#define NCHUNK 128
#define CHUNK  (NN/NCHUNK)    // 256
#define SCALE_INV_SQRT_D 0.04419417382415922f  // 1/sqrt(512)

typedef unsigned short u16;
typedef __attribute__((ext_vector_type(8))) short bf16x8;
typedef __attribute__((ext_vector_type(4))) float f32x4;

#define MFMA(a,b,c) __builtin_amdgcn_mfma_f32_16x16x32_bf16((a),(b),(c),0,0,0)

__device__ __forceinline__ unsigned pack2bf(float a, float b) {
  union { float f; unsigned u; } x{a}, y{b};
  unsigned ra = (x.u + 0x7FFFu + ((x.u >> 16) & 1u)) >> 16;
  unsigned rb = (y.u + 0x7FFFu + ((y.u >> 16) & 1u)) >> 16;
  return ra | (rb << 16);
}
// v_cvt_pk_bf16_f32 path (RNE, 1 instr per 2 values)
__device__ __forceinline__ unsigned cvt2(float a, float b) {
  union { __hip_bfloat162 h; unsigned u; } x;
  x.h = __float22bfloat162_rn(make_float2(a, b));
  return x.u;
}
__device__ __forceinline__ u16 f2bf(float a) {
  union { float f; unsigned u; } x{a};
  return (u16)((x.u + 0x7FFFu + ((x.u >> 16) & 1u)) >> 16);
}
__device__ __forceinline__ float bf2f(u16 u) {
  union { unsigned u; float f; } x; x.u = ((unsigned)u) << 16; return x.f;
}

__device__ __forceinline__ float block_reduce_sum_256(float v, float* sred) {
  #pragma unroll
  for (int off = 32; off; off >>= 1) v += __shfl_down(v, off);
  const int lane = threadIdx.x & 63, w = threadIdx.x >> 6;
  if (lane == 0) sred[w] = v;
  __syncthreads();
  float r = sred[0] + sred[1] + sred[2] + sred[3];
  __syncthreads();
  return r;
}

// ---------- prepass: Bf pack (bid<768) | pnb pack with inline proto-norm ----------
__global__ __launch_bounds__(64) void pre_kernel(
    const float* __restrict__ W, const float* __restrict__ prot,
    uint4* __restrict__ Bf, uint4* __restrict__ pnb) {
  const int bid = blockIdx.x;
  const int lane = threadIdx.x;
  if (bid < 768) {
    // Bf[nf*24+ks][lane]: n = nf*16 + (lane&15), k = ks*32 + (lane>>4)*8 + j
    const int nf = bid / 24, ks = bid % 24;
    const int n = nf*16 + (lane & 15);
    const int kb = ks*32 + (lane >> 4)*8;
    unsigned r0 = pack2bf(W[(size_t)(kb+0)*DD + n], W[(size_t)(kb+1)*DD + n]);
    unsigned r1 = pack2bf(W[(size_t)(kb+2)*DD + n], W[(size_t)(kb+3)*DD + n]);
    unsigned r2 = pack2bf(W[(size_t)(kb+4)*DD + n], W[(size_t)(kb+5)*DD + n]);
    unsigned r3 = pack2bf(W[(size_t)(kb+6)*DD + n], W[(size_t)(kb+7)*DD + n]);
    Bf[(size_t)bid*64 + lane] = make_uint4(r0, r1, r2, r3);
    return;
  }
  // pnb[ks 0..15][lane]: p = lane&15, k = ks*32 + (lane>>4)*8 + j, normalized
  const int ks = bid - 768;
  const int p = lane & 15, seg = lane >> 4;
  float ssq = 0.f;
  for (int d = seg*128; d < seg*128 + 128; d += 4) {
    float4 v = *(const float4*)&prot[p*DD + d];
    ssq += v.x*v.x + v.y*v.y + v.z*v.z + v.w*v.w;
  }
  ssq += __shfl_xor(ssq, 16);
  ssq += __shfl_xor(ssq, 32);
  const float rnp = 1.f / fmaxf(sqrtf(ssq), 1e-12f);
  const int kb = ks*32 + seg*8;
  float v[8];
  #pragma unroll
  for (int j = 0; j < 8; ++j) v[j] = prot[p*DD + kb + j] * rnp;
  pnb[ks*64 + lane] = make_uint4(pack2bf(v[0],v[1]), pack2bf(v[2],v[3]),
                                 pack2bf(v[4],v[5]), pack2bf(v[6],v[7]));
}

// ---------- GEMM: BM=256, BN=256, BK=64, 512 thr = 8 waves (2m x 4n) ----------
// m201-style quadrant interleave: per kt, stage A-regs + ALL B gloads up front,
// bfr[8] held in registers for the whole kt, MFMA in 4 quadrants with the A-pack
// placed between quadrants, ONE __syncthreads per kt (drains are pre-covered).
__global__ __launch_bounds__(512, 2) void gemm_kernel(
    const float* __restrict__ Xs, const float* __restrict__ Xl,
    const uint4* __restrict__ Bf, const float* __restrict__ bias,
    u16* __restrict__ proj, float* __restrict__ ssqp2) {
  __shared__ __align__(16) unsigned char lds[131072]; // A: 2x32K @0, B: 2x32K @65536
  const int t = threadIdx.x, lane = t & 63, wid = t >> 6;
  const int wm = wid >> 2, wn = wid & 3;              // 2m x 4n, wave tile 128x64
  const int cl = lane & 15, cg = lane >> 4;
  const int id = blockIdx.x;
  const int swz = (id & 7) * 128 + (id >> 3);   // bijective (1024 = 8*128)
  const int mb = swz >> 1, nb = swz & 1;        // nb-pair of one mb on one XCD
  const int m0g = mb * 256;                     // global row over both sides
  const float* Xb = (m0g < MTOT) ? Xs : Xl;     // 65536 % 256 == 0: no straddle
  const int m0l = m0g & (MTOT - 1);
  const int n0 = nb * 256;
  // A staging: thread t covers row r = t>>1, k-half kh1 = t&1 (32 k's)
  const int r = t >> 1, kh1 = t & 1;
  const float* gA = Xb + (size_t)(m0l + r) * DIN + kh1 * 32;
  const int abase = (((r >> 4) * 2 + kh1) << 10) + ((r & 15) << 4);

  f32x4 acc[8][4] = {};

#define STAGE_B(ktx, buf) \
  { _Pragma("unroll") \
    for (int q_ = 0; q_ < 4; ++q_) { \
      const int c_ = q_*8 + wid; \
      const uint4* src_ = Bf + ((size_t)((nb*16 + (c_>>1))*24 + (ktx)*2 + (c_&1)))*64 + lane; \
      __builtin_amdgcn_global_load_lds( \
          (const __attribute__((address_space(1))) void*)src_, \
          (__attribute__((address_space(3))) void*)(lds + 65536 + (buf)*32768 + c_*1024 + lane*16), \
          16, 0, 0); \
    } }
#define PACK_A(dstbuf) \
  { _Pragma("unroll") \
    for (int p4_ = 0; p4_ < 4; ++p4_) { \
      *(uint4*)(lds + (dstbuf)*32768 + abase + p4_*256) = make_uint4( \
          cvt2(va[2*p4_].x,   va[2*p4_].y),   cvt2(va[2*p4_].z,   va[2*p4_].w), \
          cvt2(va[2*p4_+1].x, va[2*p4_+1].y), cvt2(va[2*p4_+1].z, va[2*p4_+1].w)); \
    } }

  {  // prologue: kt=0 into buf 0
    float4 va[8];
    #pragma unroll
    for (int q = 0; q < 8; ++q) va[q] = *(const float4*)(gA + q*4);
    STAGE_B(0, 0);
    PACK_A(0);
    __syncthreads();
  }
  for (int kt = 0; kt < 12; ++kt) {
    const int cur = kt & 1;
    float4 va[8];
    if (kt < 11) {
      #pragma unroll
      for (int q = 0; q < 8; ++q) va[q] = *(const float4*)(gA + (kt+1)*64 + q*4);
      STAGE_B(kt + 1, cur ^ 1);
    }
    const int Ab = cur*32768, Bb2 = 65536 + cur*32768;
    // B fragments for the whole kt held in registers (read once)
    bf16x8 bfr[8];
    #pragma unroll
    for (int j = 0; j < 4; ++j)
      #pragma unroll
      for (int ksl = 0; ksl < 2; ++ksl)
        bfr[j*2 + ksl] = *(const bf16x8*)(lds + Bb2 + (((wn*4 + j)*2 + ksl) << 10) + lane*16);
    // 4 quadrants of 16 MFMA; A-pack for kt+1 placed after quadrant 1
    #pragma unroll
    for (int qd = 0; qd < 4; ++qd) {
      bf16x8 af[4];
      #pragma unroll
      for (int h = 0; h < 2; ++h) {
        const int mi = qd*2 + h;
        af[h*2+0] = *(const bf16x8*)(lds + Ab + (((wm*8 + mi)*2 + 0) << 10) + lane*16);
        af[h*2+1] = *(const bf16x8*)(lds + Ab + (((wm*8 + mi)*2 + 1) << 10) + lane*16);
      }
      #pragma unroll
      for (int h = 0; h < 2; ++h)
        #pragma unroll
        for (int ksl = 0; ksl < 2; ++ksl)
          #pragma unroll
          for (int j = 0; j < 4; ++j)
            acc[qd*2+h][j] = MFMA(af[h*2+ksl], bfr[j*2+ksl], acc[qd*2+h][j]);
      if (qd == 1 && kt < 11) PACK_A(cur ^ 1);
    }
    __syncthreads();   // reads done; staged kt+1 (issued ~whole-kt ago) drained cheaply
  }
#undef STAGE_B
#undef PACK_A
  // ---- epilogue: bias, proj bf16 store, per-row ssq partial (this nb) ----
  float* ssqred = (float*)lds;                  // [256][4]
  float bv[4];
  #pragma unroll
  for (int j = 0; j < 4; ++j) bv[j] = bias[n0 + wn*64 + j*16 + cl];
  #pragma unroll
  for (int i = 0; i < 8; ++i) {
    #pragma unroll
    for (int rr = 0; rr < 4; ++rr) {
      const int rowl = wm*128 + i*16 + cg*4 + rr;
      u16* pr = proj + (size_t)(m0g + rowl) * DD + n0 + wn*64 + cl;
      float sq = 0.f;
      #pragma unroll
      for (int j = 0; j < 4; ++j) {
        float val = acc[i][j][rr] + bv[j];
        pr[j*16] = f2bf(val);
        sq += val * val;
      }
      sq += __shfl_xor(sq, 1); sq += __shfl_xor(sq, 2);
      sq += __shfl_xor(sq, 4); sq += __shfl_xor(sq, 8);
      if (cl == 0) ssqred[rowl*4 + wn] = sq;
    }
  }
  __syncthreads();
  if (t < 256) {
    float ss = ssqred[t*4+0] + ssqred[t*4+1] + ssqred[t*4+2] + ssqred[t*4+3];
    ssqp2[(size_t)(m0g + t) * 2 + nb] = ss;
  }
}

// ---------- scores via MFMA: rnorm from ssqp2, exp(score), espart, wbufe ----------
__global__ __launch_bounds__(256) void scores_kernel(
    const u16* __restrict__ proj, const uint4* __restrict__ pnb,
    const float* __restrict__ ssqp2, float* __restrict__ rnormb,
    u16* __restrict__ wbufe, float* __restrict__ espart) {
  __shared__ float esp[4][16];
  __shared__ u16 sbuf[128][18];   // padded: write by col, read by row
  const int t = threadIdx.x, lane = t & 63, wave = t >> 6;
  const int cl = lane & 15, cg = lane >> 4;
  bf16x8 pf[16];
  #pragma unroll
  for (int ks = 0; ks < 16; ++ks) pf[ks] = *(const bf16x8*)(pnb + ks*64 + lane);
  const int row0b = blockIdx.x * 128;
  float esum = 0.f;
  #pragma unroll
  for (int rg = 0; rg < 2; ++rg) {
    const int row0 = row0b + wave*32 + rg*16;
    f32x4 sacc = {0.f, 0.f, 0.f, 0.f};
    #pragma unroll
    for (int ks = 0; ks < 16; ++ks) {
      bf16x8 af = *(const bf16x8*)(proj + (size_t)(row0 + cl)*DD + ks*32 + cg*8);
      sacc = MFMA(af, pf[ks], sacc);
    }
    #pragma unroll
    for (int rr = 0; rr < 4; ++rr) {
      const int grow = row0 + cg*4 + rr;
      const float2 sp = *(const float2*)&ssqp2[(size_t)grow * 2];
      const float rn = 1.f / fmaxf(sqrtf(sp.x + sp.y), 1e-12f);
      if (cl == 0) rnormb[grow] = rn;
      const float sc = sacc[rr] * rn * SCALE_INV_SQRT_D;
      const float e = expf(sc);      // |sc| <= ~0.0442: no max-subtract needed
      esum += e;
      sbuf[wave*32 + rg*16 + cg*4 + rr][cl] = f2bf(e);
    }
  }
  esum += __shfl_xor(esum, 16);
  esum += __shfl_xor(esum, 32);
  if (lane < 16) esp[wave][lane] = esum;
  __syncthreads();
  if (t < 16)
    espart[(size_t)blockIdx.x * PP + t] = esp[0][t] + esp[1][t] + esp[2][t] + esp[3][t];
  {  // coalesced wbufe store: p = t>>4, 8 u16 per thread
    const int p = t >> 4, i8 = (t & 15) * 8;
    const int sbp = row0b >> 15, nb0 = row0b & (NN - 1);
    u16 tmp[8];
    #pragma unroll
    for (int k = 0; k < 8; ++k) tmp[k] = sbuf[i8 + k][p];
    *(uint4*)&wbufe[(size_t)(sbp*PP + p) * NN + nb0 + i8] = *(const uint4*)tmp;
  }
}

// ---------- reduce expsum partials -> iSrow[(side*2+b)*16+p]: grid 64 ----------
__global__ __launch_bounds__(256) void isum_kernel(const float* __restrict__ espart,
                                                   float* __restrict__ iSrow) {
  __shared__ float sred[4];
  const int bid = blockIdx.x, sbp = bid >> 4, p = bid & 15;
  const int t = threadIdx.x;
  float s = espart[(size_t)(sbp*256 + t)*PP + p];
  s = block_reduce_sum_256(s, sred);
  if (t == 0) iSrow[bid] = 1.f / s;
}

// ---------- attended (fused wsum), both sides: grid (NCHUNK, 4) ----------
__global__ __launch_bounds__(256) void attended_kernel(
    const u16* __restrict__ proj, const u16* __restrict__ wbufe,
    const float* __restrict__ rnormb, const float* __restrict__ iSrow,
    float* __restrict__ part) {
  __shared__ float wl[CHUNK];
  __shared__ float iSl[PP];
  const int sb = blockIdx.y, cid = blockIdx.x, t = threadIdx.x;
  const int nbase = cid * CHUNK;
  if (t < PP) iSl[t] = iSrow[sb*PP + t];
  __syncthreads();
  if (t < CHUNK) {
    const int n = nbase + t;
    float s = 0.f;
    #pragma unroll
    for (int p = 0; p < PP; ++p)
      s += bf2f(wbufe[(size_t)(sb*PP + p)*NN + n]) * iSl[p];
    wl[t] = s * rnormb[sb*NN + n] * (1.f / PP);
  }
  __syncthreads();
  float a0 = 0.f, a1 = 0.f;
  const u16* pb = proj + ((size_t)sb * NN + nbase) * DD + 2*t;
  #pragma unroll 8
  for (int n = 0; n < CHUNK; ++n) {
    unsigned uu = *(const unsigned*)(pb + (size_t)n * DD);
    float w = wl[n];
    a0 += w * bf2f((u16)uu);
    a1 += w * bf2f((u16)(uu >> 16));
  }
  *(float2*)&part[((size_t)(sb*NCHUNK + cid))*DD + 2*t] = make_float2(a0, a1);
}

// ---------- reduce chunks -> fraw[sb][d]: grid (4 dchunks, 4 sb) ----------
__global__ __launch_bounds__(256) void featred_kernel(
    const float* __restrict__ part, float* __restrict__ fraw) {
  __shared__ float red[2][128];
  const int sb = blockIdx.y, d0 = blockIdx.x * 128, t = threadIdx.x;
  const int dl = t & 127, half = t >> 7;
  float s = 0.f;
  for (int c = half*64; c < half*64 + 64; ++c)
    s += part[((size_t)(sb*NCHUNK + c))*DD + d0 + dl];
  red[half][dl] = s;
  __syncthreads();
  if (t < 128) fraw[sb*DD + d0 + t] = red[0][t] + red[1][t];
}

// ---------- final: normalize feats, logits, softmax, argmax, loss ----------
__global__ __launch_bounds__(256) void final_kernel(
    const float* __restrict__ fraw, const float* __restrict__ textL,
    const float* __restrict__ textH, const int* __restrict__ label,
    float* __restrict__ out) {
  __shared__ float sred[4];
  const int t = threadIdx.x;
  const float* frawL = fraw;            // sb 0,1 = x_s b0,b1
  const float* frawH = fraw + 2*DD;     // sb 2,3 = x_l b0,b1
  float invL[2], invH[2];
  #pragma unroll
  for (int b = 0; b < 2; ++b) {
    float v = 0.f;
    for (int d = t; d < DD; d += 256) { float x = frawL[b*DD + d]; v += x*x; }
    float ss = block_reduce_sum_256(v, sred);
    invL[b] = 1.f / fmaxf(sqrtf(ss), 1e-12f);
    v = 0.f;
    for (int d = t; d < DD; d += 256) { float x = frawH[b*DD + d]; v += x*x; }
    ss = block_reduce_sum_256(v, sred);
    invH[b] = 1.f / fmaxf(sqrtf(ss), 1e-12f);
  }
  float lg[2][2];
  #pragma unroll
  for (int b = 0; b < 2; ++b)
    #pragma unroll
    for (int c = 0; c < 2; ++c) {
      float v = 0.f;
      for (int d = t; d < DD; d += 256)
        v += frawL[b*DD + d] * invL[b] * textL[c*DD + d]
           + frawH[b*DD + d] * invH[b] * textH[c*DD + d];
      lg[b][c] = block_reduce_sum_256(v, sred);
    }
  if (t == 0) {
    float loss = 0.f;
    #pragma unroll
    for (int b = 0; b < 2; ++b) {
      const float m  = fmaxf(lg[b][0], lg[b][1]);
      const float lse = m + logf(expf(lg[b][0]-m) + expf(lg[b][1]-m));
      out[b*2+0] = expf(lg[b][0]-lse); out[b*2+1] = expf(lg[b][1]-lse);
      out[4+b] = (lg[b][1] > lg[b][0]) ? 1.f : 0.f;
      loss += -(lg[b][label[b]] - lse);
    }
    out[6] = loss * 0.5f;
  }
}

extern "C" void kernel_launch(void* const* d_in, const int* in_sizes, int n_in,
                              void* d_out, int out_size, void* d_ws, size_t ws_size,
                              hipStream_t stream) {
  (void)in_sizes; (void)n_in; (void)out_size; (void)ws_size;
  const float* x_s  = (const float*)d_in[0];
  const float* x_l  = (const float*)d_in[2];
  const float* Wp   = (const float*)d_in[4];
  const float* bp   = (const float*)d_in[5];
  const float* prot = (const float*)d_in[6];
  const float* tL   = (const float*)d_in[7];
  const float* tH   = (const float*)d_in[8];
  const int*   label= (const int*)d_in[9];
  float* out = (float*)d_out;

  unsigned char* w8 = (unsigned char*)d_ws;
  u16*   proj   = (u16*)  (w8);                  // 134,217,728 (both sides)
  u16*   wbufe  = (u16*)  (w8 + 134217728);      //   4,194,304  exp(score) bf16 [4][16][NN]
  float* part   = (float*)(w8 + 138412032);      //   1,048,576  [4][NCHUNK][DD]
  float* rnormb = (float*)(w8 + 139460608);      //     524,288  [131072]
  float* ssqp2  = (float*)(w8 + 139984896);      //   1,048,576  [131072][2]
  float* espart = (float*)(w8 + 141033472);      //      65,536  [1024][16]
  float* iSrow  = (float*)(w8 + 141099008);      //       1,024
  uint4* Bf     = (uint4*)(w8 + 141100032);      //     786,432
  uint4* pnb    = (uint4*)(w8 + 141886464);      //      16,384
  float* fraw   = (float*)(w8 + 141902848);      //       8,192  [4][512]

  pre_kernel<<<784, 64, 0, stream>>>(Wp, prot, Bf, pnb);
  gemm_kernel<<<1024, 512, 0, stream>>>(x_s, x_l, Bf, bp, proj, ssqp2);
  scores_kernel<<<MALL/128, 256, 0, stream>>>(proj, pnb, ssqp2, rnormb, wbufe, espart);
  isum_kernel<<<64, 256, 0, stream>>>(espart, iSrow);
  attended_kernel<<<dim3(NCHUNK, 4), 256, 0, stream>>>(proj, wbufe, rnormb, iSrow, part);
  featred_kernel<<<dim3(4, 4), 256, 0, stream>>>(part, fraw);
  final_kernel<<<1, 256, 0, stream>>>(fraw, tL, tH, label, out);
}

// Round 19
// 217.759 us; speedup vs baseline: 1.3649x; 1.3649x over previous
//
#include <hip/hip_runtime.h>
#include <hip/hip_bf16.h>
#include <math.h>

#define BB   2
#define NN   32768
#define DIN  768
#define DD   512
#define PP   16
#define MTOT (BB*NN)          // rows per side
#define MALL (2*MTOT)         // both sides
#define NCHUNK 128
#define CHUNK  (NN/NCHUNK)    // 256
#define SCALE_INV_SQRT_D 0.04419417382415922f  // 1/sqrt(512)

typedef unsigned short u16;
typedef __attribute__((ext_vector_type(8))) short bf16x8;
typedef __attribute__((ext_vector_type(4))) float f32x4;

#define MFMA(a,b,c) __builtin_amdgcn_mfma_f32_16x16x32_bf16((a),(b),(c),0,0,0)

__device__ __forceinline__ unsigned pack2bf(float a, float b) {
  union { float f; unsigned u; } x{a}, y{b};
  unsigned ra = (x.u + 0x7FFFu + ((x.u >> 16) & 1u)) >> 16;
  unsigned rb = (y.u + 0x7FFFu + ((y.u >> 16) & 1u)) >> 16;
  return ra | (rb << 16);
}
// v_cvt_pk_bf16_f32 path (RNE, 1 instr per 2 values)
__device__ __forceinline__ unsigned cvt2(float a, float b) {
  union { __hip_bfloat162 h; unsigned u; } x;
  x.h = __float22bfloat162_rn(make_float2(a, b));
  return x.u;
}
__device__ __forceinline__ u16 f2bf(float a) {
  union { float f; unsigned u; } x{a};
  return (u16)((x.u + 0x7FFFu + ((x.u >> 16) & 1u)) >> 16);
}
__device__ __forceinline__ float bf2f(u16 u) {
  union { unsigned u; float f; } x; x.u = ((unsigned)u) << 16; return x.f;
}

__device__ __forceinline__ float block_reduce_sum_256(float v, float* sred) {
  #pragma unroll
  for (int off = 32; off; off >>= 1) v += __shfl_down(v, off);
  const int lane = threadIdx.x & 63, w = threadIdx.x >> 6;
  if (lane == 0) sred[w] = v;
  __syncthreads();
  float r = sred[0] + sred[1] + sred[2] + sred[3];
  __syncthreads();
  return r;
}

// ---------- prepass: Bf pack (bid<768) | pnb pack with inline proto-norm ----------
__global__ __launch_bounds__(64) void pre_kernel(
    const float* __restrict__ W, const float* __restrict__ prot,
    uint4* __restrict__ Bf, uint4* __restrict__ pnb) {
  const int bid = blockIdx.x;
  const int lane = threadIdx.x;
  if (bid < 768) {
    // Bf[nf*24+ks][lane]: n = nf*16 + (lane&15), k = ks*32 + (lane>>4)*8 + j
    const int nf = bid / 24, ks = bid % 24;
    const int n = nf*16 + (lane & 15);
    const int kb = ks*32 + (lane >> 4)*8;
    unsigned r0 = pack2bf(W[(size_t)(kb+0)*DD + n], W[(size_t)(kb+1)*DD + n]);
    unsigned r1 = pack2bf(W[(size_t)(kb+2)*DD + n], W[(size_t)(kb+3)*DD + n]);
    unsigned r2 = pack2bf(W[(size_t)(kb+4)*DD + n], W[(size_t)(kb+5)*DD + n]);
    unsigned r3 = pack2bf(W[(size_t)(kb+6)*DD + n], W[(size_t)(kb+7)*DD + n]);
    Bf[(size_t)bid*64 + lane] = make_uint4(r0, r1, r2, r3);
    return;
  }
  // pnb[ks 0..15][lane]: p = lane&15, k = ks*32 + (lane>>4)*8 + j, normalized
  const int ks = bid - 768;
  const int p = lane & 15, seg = lane >> 4;
  float ssq = 0.f;
  for (int d = seg*128; d < seg*128 + 128; d += 4) {
    float4 v = *(const float4*)&prot[p*DD + d];
    ssq += v.x*v.x + v.y*v.y + v.z*v.z + v.w*v.w;
  }
  ssq += __shfl_xor(ssq, 16);
  ssq += __shfl_xor(ssq, 32);
  const float rnp = 1.f / fmaxf(sqrtf(ssq), 1e-12f);
  const int kb = ks*32 + seg*8;
  float v[8];
  #pragma unroll
  for (int j = 0; j < 8; ++j) v[j] = prot[p*DD + kb + j] * rnp;
  pnb[ks*64 + lane] = make_uint4(pack2bf(v[0],v[1]), pack2bf(v[2],v[3]),
                                 pack2bf(v[4],v[5]), pack2bf(v[6],v[7]));
}

// ---------- GEMM: BM=128, BN=512, BK=64, 1024 thr = 16 waves (2m x 8n) ----------
// grid 1024. Wave tile 64x64 (acc 64 AGPR) -> 4 waves/SIMD. A: 2x16KB dbuf LDS
// (XOR-swizzled); B: 2x64KB dbuf via global_load_lds. ONE barrier per kt.
// (Best-measured config: R14, gemm 184 us. 11 structural variants bracket this.)
__global__ __launch_bounds__(1024, 4) void gemm_kernel(
    const float* __restrict__ Xs, const float* __restrict__ Xl,
    const uint4* __restrict__ Bf, const float* __restrict__ bias,
    u16* __restrict__ proj, float* __restrict__ rnormb) {
  __shared__ __align__(16) unsigned char lds[163840]; // A: 2x16K @0, B: 2x64K @32K
  const int t = threadIdx.x, lane = t & 63, wid = t >> 6;   // 16 waves
  const int wm = wid >> 3, wn = wid & 7;                    // 2m x 8n
  const int cl = lane & 15, cg = lane >> 4;
  const int m0g = blockIdx.x * 128;             // global row over both sides
  const float* Xb = (m0g < MTOT) ? Xs : Xl;     // 65536 % 128 == 0: no straddle
  const int m0l = m0g & (MTOT - 1);
  // A staging: row r = t>>3 (128 rows), k8 = (t&7)*8 (8 k's = 2 float4)
  const int r = t >> 3, k8g = (t & 7) * 8;
  const float* gA = Xb + (size_t)(m0l + r) * DIN + k8g;
  const int aksl = k8g >> 5, acg = (k8g >> 3) & 3;
  const int awoff = ((r >> 4) * 2 + aksl) * 1024 + acg * 256
                  + (((r & 15) ^ ((acg << 1) | aksl)) << 4);   // XOR swizzle

  f32x4 acc[4][4] = {};

#define STAGE_B(ktx, buf) \
  { _Pragma("unroll") \
    for (int q_ = 0; q_ < 4; ++q_) { \
      const int c_ = q_*16 + wid; \
      const uint4* src_ = Bf + ((size_t)((c_>>1)*24 + (ktx)*2 + (c_&1)))*64 + lane; \
      __builtin_amdgcn_global_load_lds( \
          (const __attribute__((address_space(1))) void*)src_, \
          (__attribute__((address_space(3))) void*)(lds + 32768 + (buf)*65536 + c_*1024 + lane*16), \
          16, 0, 0); \
    } }

  {  // prologue: B(0)->buf0, A(0)->abuf0
    STAGE_B(0, 0);
    float4 a0 = *(const float4*)gA;
    float4 a1 = *(const float4*)(gA + 4);
    *(uint4*)(lds + awoff) = make_uint4(cvt2(a0.x,a0.y), cvt2(a0.z,a0.w),
                                        cvt2(a1.x,a1.y), cvt2(a1.z,a1.w));
    __syncthreads();
  }
  for (int kt = 0; kt < 12; ++kt) {
    const int cur = kt & 1;
    float4 a0, a1;
    if (kt < 11) {
      STAGE_B(kt + 1, cur ^ 1);                  // into B[cur^1]; drains at barrier
      a0 = *(const float4*)(gA + (kt + 1) * 64); // HBM latency covered by MFMAs
      a1 = *(const float4*)(gA + (kt + 1) * 64 + 4);
    }
    #pragma unroll
    for (int ksl = 0; ksl < 2; ++ksl) {
      bf16x8 af[4], bfr[4];
      #pragma unroll
      for (int i = 0; i < 4; ++i)
        af[i] = *(const bf16x8*)(lds + cur*16384 + ((wm*4 + i)*2 + ksl)*1024 + cg*256
                                     + ((cl ^ ((cg << 1) | ksl)) << 4));
      #pragma unroll
      for (int j = 0; j < 4; ++j)
        bfr[j] = *(const bf16x8*)(lds + 32768 + cur*65536
                                      + ((wn*4 + j)*2 + ksl)*1024 + lane*16);
      #pragma unroll
      for (int i = 0; i < 4; ++i)
        #pragma unroll
        for (int j = 0; j < 4; ++j)
          acc[i][j] = MFMA(af[i], bfr[j], acc[i][j]);
    }
    if (kt < 11) {                               // A(kt+1) -> A[cur^1] (write-late)
      *(uint4*)(lds + (cur^1)*16384 + awoff) =
          make_uint4(cvt2(a0.x,a0.y), cvt2(a0.z,a0.w),
                     cvt2(a1.x,a1.y), cvt2(a1.z,a1.w));
    }
    __syncthreads();   // single barrier: cur reads done, B[cur^1] drained, A[cur^1] visible
  }
#undef STAGE_B
  // ---- epilogue: bias, proj bf16 store, ssq -> rnormb (reuse LDS) ----
  float* ssqred = (float*)lds;                   // [128][8]
  float bv[4];
  #pragma unroll
  for (int j = 0; j < 4; ++j) bv[j] = bias[wn*64 + j*16 + cl];
  #pragma unroll
  for (int i = 0; i < 4; ++i) {
    #pragma unroll
    for (int rr = 0; rr < 4; ++rr) {
      const int rowl = wm*64 + i*16 + cg*4 + rr;
      u16* pr = proj + (size_t)(m0g + rowl) * DD + wn*64 + cl;
      float sq = 0.f;
      #pragma unroll
      for (int j = 0; j < 4; ++j) {
        float val = acc[i][j][rr] + bv[j];
        pr[j*16] = f2bf(val);
        sq += val * val;
      }
      sq += __shfl_xor(sq, 1); sq += __shfl_xor(sq, 2);
      sq += __shfl_xor(sq, 4); sq += __shfl_xor(sq, 8);
      if (cl == 0) ssqred[rowl*8 + wn] = sq;
    }
  }
  __syncthreads();
  if (t < 128) {
    float ss = 0.f;
    #pragma unroll
    for (int w = 0; w < 8; ++w) ss += ssqred[t*8 + w];
    rnormb[m0g + t] = 1.f / fmaxf(sqrtf(ss), 1e-12f);
  }
}

// ---------- scores via MFMA: exp(score), espart, wbufe; grid 1024 x 256 thr ----------
__global__ __launch_bounds__(256) void scores_kernel(
    const u16* __restrict__ proj, const uint4* __restrict__ pnb,
    const float* __restrict__ rnormb, u16* __restrict__ wbufe,
    float* __restrict__ espart) {
  __shared__ float esp[4][16];
  __shared__ u16 sbuf[128][18];   // padded: write by col, read by row
  const int t = threadIdx.x, lane = t & 63, wave = t >> 6;
  const int cl = lane & 15, cg = lane >> 4;
  bf16x8 pf[16];
  #pragma unroll
  for (int ks = 0; ks < 16; ++ks) pf[ks] = *(const bf16x8*)(pnb + ks*64 + lane);
  const int row0b = blockIdx.x * 128;
  float esum = 0.f;
  #pragma unroll
  for (int rg = 0; rg < 2; ++rg) {
    const int row0 = row0b + wave*32 + rg*16;
    f32x4 sacc = {0.f, 0.f, 0.f, 0.f};
    #pragma unroll
    for (int ks = 0; ks < 16; ++ks) {
      bf16x8 af = *(const bf16x8*)(proj + (size_t)(row0 + cl)*DD + ks*32 + cg*8);
      sacc = MFMA(af, pf[ks], sacc);
    }
    #pragma unroll
    for (int rr = 0; rr < 4; ++rr) {
      const int grow = row0 + cg*4 + rr;
      const float sc = sacc[rr] * rnormb[grow] * SCALE_INV_SQRT_D;
      const float e = expf(sc);      // |sc| <= ~0.0442: no max-subtract needed
      esum += e;
      sbuf[wave*32 + rg*16 + cg*4 + rr][cl] = f2bf(e);
    }
  }
  esum += __shfl_xor(esum, 16);
  esum += __shfl_xor(esum, 32);
  if (lane < 16) esp[wave][lane] = esum;
  __syncthreads();
  if (t < 16)
    espart[(size_t)blockIdx.x * PP + t] = esp[0][t] + esp[1][t] + esp[2][t] + esp[3][t];
  {  // coalesced wbufe store: p = t>>4, 8 u16 per thread
    const int p = t >> 4, i8 = (t & 15) * 8;
    const int sbp = row0b >> 15, nb0 = row0b & (NN - 1);
    u16 tmp[8];
    #pragma unroll
    for (int k = 0; k < 8; ++k) tmp[k] = sbuf[i8 + k][p];
    *(uint4*)&wbufe[(size_t)(sbp*PP + p) * NN + nb0 + i8] = *(const uint4*)tmp;
  }
}

// ---------- reduce expsum partials -> iSrow[(side*2+b)*16+p]: grid 64 ----------
__global__ __launch_bounds__(256) void isum_kernel(const float* __restrict__ espart,
                                                   float* __restrict__ iSrow) {
  __shared__ float sred[4];
  const int bid = blockIdx.x, sbp = bid >> 4, p = bid & 15;
  const int t = threadIdx.x;
  float s = espart[(size_t)(sbp*256 + t)*PP + p];
  s = block_reduce_sum_256(s, sred);
  if (t == 0) iSrow[bid] = 1.f / s;
}

// ---------- attended (fused wsum), both sides: grid (NCHUNK, 4) ----------
__global__ __launch_bounds__(256) void attended_kernel(
    const u16* __restrict__ proj, const u16* __restrict__ wbufe,
    const float* __restrict__ rnormb, const float* __restrict__ iSrow,
    float* __restrict__ part) {
  __shared__ float wl[CHUNK];
  __shared__ float iSl[PP];
  const int sb = blockIdx.y, cid = blockIdx.x, t = threadIdx.x;
  const int nbase = cid * CHUNK;
  if (t < PP) iSl[t] = iSrow[sb*PP + t];
  __syncthreads();
  if (t < CHUNK) {
    const int n = nbase + t;
    float s = 0.f;
    #pragma unroll
    for (int p = 0; p < PP; ++p)
      s += bf2f(wbufe[(size_t)(sb*PP + p)*NN + n]) * iSl[p];
    wl[t] = s * rnormb[sb*NN + n] * (1.f / PP);
  }
  __syncthreads();
  float a0 = 0.f, a1 = 0.f;
  const u16* pb = proj + ((size_t)sb * NN + nbase) * DD + 2*t;
  #pragma unroll 8
  for (int n = 0; n < CHUNK; ++n) {
    unsigned uu = *(const unsigned*)(pb + (size_t)n * DD);
    float w = wl[n];
    a0 += w * bf2f((u16)uu);
    a1 += w * bf2f((u16)(uu >> 16));
  }
  *(float2*)&part[((size_t)(sb*NCHUNK + cid))*DD + 2*t] = make_float2(a0, a1);
}

// ---------- reduce chunks -> fraw[sb][d]: grid (4 dchunks, 4 sb) ----------
__global__ __launch_bounds__(256) void featred_kernel(
    const float* __restrict__ part, float* __restrict__ fraw) {
  __shared__ float red[2][128];
  const int sb = blockIdx.y, d0 = blockIdx.x * 128, t = threadIdx.x;
  const int dl = t & 127, half = t >> 7;
  float s = 0.f;
  for (int c = half*64; c < half*64 + 64; ++c)
    s += part[((size_t)(sb*NCHUNK + c))*DD + d0 + dl];
  red[half][dl] = s;
  __syncthreads();
  if (t < 128) fraw[sb*DD + d0 + t] = red[0][t] + red[1][t];
}

// ---------- final: normalize feats, logits, softmax, argmax, loss ----------
__global__ __launch_bounds__(256) void final_kernel(
    const float* __restrict__ fraw, const float* __restrict__ textL,
    const float* __restrict__ textH, const int* __restrict__ label,
    float* __restrict__ out) {
  __shared__ float sred[4];
  const int t = threadIdx.x;
  const float* frawL = fraw;            // sb 0,1 = x_s b0,b1
  const float* frawH = fraw + 2*DD;     // sb 2,3 = x_l b0,b1
  float invL[2], invH[2];
  #pragma unroll
  for (int b = 0; b < 2; ++b) {
    float v = 0.f;
    for (int d = t; d < DD; d += 256) { float x = frawL[b*DD + d]; v += x*x; }
    float ss = block_reduce_sum_256(v, sred);
    invL[b] = 1.f / fmaxf(sqrtf(ss), 1e-12f);
    v = 0.f;
    for (int d = t; d < DD; d += 256) { float x = frawH[b*DD + d]; v += x*x; }
    ss = block_reduce_sum_256(v, sred);
    invH[b] = 1.f / fmaxf(sqrtf(ss), 1e-12f);
  }
  float lg[2][2];
  #pragma unroll
  for (int b = 0; b < 2; ++b)
    #pragma unroll
    for (int c = 0; c < 2; ++c) {
      float v = 0.f;
      for (int d = t; d < DD; d += 256)
        v += frawL[b*DD + d] * invL[b] * textL[c*DD + d]
           + frawH[b*DD + d] * invH[b] * textH[c*DD + d];
      lg[b][c] = block_reduce_sum_256(v, sred);
    }
  if (t == 0) {
    float loss = 0.f;
    #pragma unroll
    for (int b = 0; b < 2; ++b) {
      const float m  = fmaxf(lg[b][0], lg[b][1]);
      const float lse = m + logf(expf(lg[b][0]-m) + expf(lg[b][1]-m));
      out[b*2+0] = expf(lg[b][0]-lse); out[b*2+1] = expf(lg[b][1]-lse);
      out[4+b] = (lg[b][1] > lg[b][0]) ? 1.f : 0.f;
      loss += -(lg[b][label[b]] - lse);
    }
    out[6] = loss * 0.5f;
  }
}

extern "C" void kernel_launch(void* const* d_in, const int* in_sizes, int n_in,
                              void* d_out, int out_size, void* d_ws, size_t ws_size,
                              hipStream_t stream) {
  (void)in_sizes; (void)n_in; (void)out_size; (void)ws_size;
  const float* x_s  = (const float*)d_in[0];
  const float* x_l  = (const float*)d_in[2];
  const float* Wp   = (const float*)d_in[4];
  const float* bp   = (const float*)d_in[5];
  const float* prot = (const float*)d_in[6];
  const float* tL   = (const float*)d_in[7];
  const float* tH   = (const float*)d_in[8];
  const int*   label= (const int*)d_in[9];
  float* out = (float*)d_out;

  unsigned char* w8 = (unsigned char*)d_ws;
  u16*   proj   = (u16*)  (w8);                  // 134,217,728 (both sides)
  u16*   wbufe  = (u16*)  (w8 + 134217728);      //   4,194,304  exp(score) bf16 [4][16][NN]
  float* part   = (float*)(w8 + 138412032);      //   1,048,576  [4][NCHUNK][DD]
  float* rnormb = (float*)(w8 + 139460608);      //     524,288  [131072]
  float* espart = (float*)(w8 + 139984896);      //      65,536  [1024][16]
  float* iSrow  = (float*)(w8 + 140050432);      //       1,024
  uint4* Bf     = (uint4*)(w8 + 140051456);      //     786,432
  uint4* pnb    = (uint4*)(w8 + 140837888);      //      16,384
  float* fraw   = (float*)(w8 + 140854272);      //       8,192  [4][512]

  pre_kernel<<<784, 64, 0, stream>>>(Wp, prot, Bf, pnb);
  gemm_kernel<<<MALL/128, 1024, 0, stream>>>(x_s, x_l, Bf, bp, proj, rnormb);
  scores_kernel<<<MALL/128, 256, 0, stream>>>(proj, pnb, rnormb, wbufe, espart);
  isum_kernel<<<64, 256, 0, stream>>>(espart, iSrow);
  attended_kernel<<<dim3(NCHUNK, 4), 256, 0, stream>>>(proj, wbufe, rnormb, iSrow, part);
  featred_kernel<<<dim3(4, 4), 256, 0, stream>>>(part, fraw);
  final_kernel<<<1, 256, 0, stream>>>(fraw, tL, tH, label, out);
}